// Round 12
// baseline (72.675 us; speedup 1.0000x reference)
//
#include <hip/hip_runtime.h>

#define NN   10000
#define NE   640000
#define DIM  128
#define NREP 8
#define CAP  64        // per-(row,rep): ~Binom(deg~64..110, 1/8) mean 8-14, P(>64)~0; guarded anyway
#define ROWS_PAD 10240
#define NTILES (NN / 16)       // 625
#define PREP_ITEMS (114688 + NN * DIM / 8)   // 274,688

typedef __attribute__((ext_vector_type(8))) short bf16x8;
typedef __attribute__((ext_vector_type(8))) unsigned short u16x8;
typedef __attribute__((ext_vector_type(4))) float f32x4;

__device__ inline unsigned short f2bf(float f) {
    unsigned u = __builtin_bit_cast(unsigned, f);
    unsigned r = (u + 0x7fffu + ((u >> 16) & 1u)) >> 16;
    return (unsigned short)r;
}
__device__ inline float bf2f(unsigned short u) {
    return __builtin_bit_cast(float, (unsigned)u << 16);
}

// ===========================================================================
// PRIMARY ws layout (bytes), total 13,193,216  (round-9 proven):
//   cnt   [8][10240] int            @ 0           (327,680)   zeroed in prep
//   bucket ushort[10000][8][64]     @ 327,680     (10,240,000) [row][rep][slot]
//   xb    ushort[1,280,000]         @ 10,567,680  (2,560,000)  bf16 of x
//   W1p   ushort[16384]             @ 13,127,680  (32,768)  bf16 MFMA-frag order
//   W2p   ushort[16384]             @ 13,160,448  (32,768)
// ===========================================================================
#define OFF_BUCKET 327680
#define OFF_XB     10567680
#define OFF_W1P    13127680
#define OFF_W2P    13160448
#define WS_NEED    13193216

// --- prep: pack W1/W2 (MFMA B-frag bf16), zero cnt, convert x -> bf16 -------
// B-frag for mfma_f32_16x16x32_bf16: lane l elem e = B[kt*32+(l>>4)*8+e][nt*16+(l&15)].
__global__ __launch_bounds__(256) void prep_kernel(
        const float* __restrict__ W1, const float* __restrict__ W2,
        const float* __restrict__ x,
        unsigned short* __restrict__ W1p, unsigned short* __restrict__ W2p,
        unsigned short* __restrict__ xb, int* __restrict__ cnt) {
    int id = blockIdx.x * 256 + threadIdx.x;
    if (id < 32768) {
        const float* W = (id < 16384) ? W1 : W2;
        unsigned short* Wp = (id < 16384) ? W1p : W2p;
        int f = id & 16383;
        int e = f & 7, lane = (f >> 3) & 63, kt = (f >> 9) & 3, nt = f >> 11;
        int kglob = kt * 32 + (lane >> 4) * 8 + e;
        int jglob = nt * 16 + (lane & 15);
        Wp[f] = f2bf(W[kglob * DIM + jglob]);
    } else if (id < 114688) {
        cnt[id - 32768] = 0;
    } else if (id < PREP_ITEMS) {
        int i = (id - 114688) * 8;
        float4 a = *reinterpret_cast<const float4*>(x + i);
        float4 b = *reinterpret_cast<const float4*>(x + i + 4);
        u16x8 pk;
        pk[0] = f2bf(a.x); pk[1] = f2bf(a.y); pk[2] = f2bf(a.z); pk[3] = f2bf(a.w);
        pk[4] = f2bf(b.x); pk[5] = f2bf(b.y); pk[6] = f2bf(b.z); pk[7] = f2bf(b.w);
        *reinterpret_cast<u16x8*>(xb + i) = pk;
    }
}

// --- single pass: bucket[row][rep][slot] = col; 8-way replicated counters ---
__global__ __launch_bounds__(256) void fill_direct_kernel(
        const int* __restrict__ ei, int* __restrict__ cnt,
        unsigned short* __restrict__ bucket) {
    int e = blockIdx.x * 256 + threadIdx.x;
    if (e < NE) {
        int2 rc = *reinterpret_cast<const int2*>(ei + 2 * e);
        int rep = blockIdx.x & (NREP - 1);
        int slot = atomicAdd(&cnt[rep * ROWS_PAD + rc.x], 1);
        if (slot < CAP)
            bucket[(size_t)rc.x * (NREP * CAP) + rep * CAP + slot] = (unsigned short)rc.y;
    }
}

// --- fused gather + MLP, LDS-staged colids (round-9 proven) -----------------
__global__ __launch_bounds__(256) void gather_mlp_kernel(
        const unsigned short* __restrict__ xb,
        const int* __restrict__ cnt,
        const unsigned short* __restrict__ bucket,
        const unsigned short* __restrict__ W1p,
        const unsigned short* __restrict__ W2p,
        const float* __restrict__ b1,
        const float* __restrict__ b2,
        float* __restrict__ out) {
    __shared__ __align__(16) unsigned short aggs[16][136];
    __shared__ __align__(16) unsigned short hbuf[16][136];
    __shared__ __align__(16) unsigned short clist[16][NREP * CAP];
    __shared__ int mcnt[16][NREP];
    __shared__ int moff[16][NREP + 1];

    const int row0 = blockIdx.x * 16;
    const int t = threadIdx.x;

    // ---- stage 1: per-(node,rep) clamped counts ----
    if (t < 16 * NREP) {
        int n = t >> 3, rep = t & 7;
        int m = cnt[rep * ROWS_PAD + row0 + n];
        mcnt[n][rep] = (m > CAP) ? CAP : m;
    }
    __syncthreads();
    if (t < 16) {
        int run = 0;
        #pragma unroll
        for (int rep = 0; rep < NREP; ++rep) {
            moff[t][rep] = run;
            run += mcnt[t][rep];
        }
        moff[t][NREP] = run;   // = degree of node t
    }
    __syncthreads();

    // ---- stage 2: compact bucket segments -> dense clist[node][0..deg) ----
    {
        const int n = t >> 4, l16 = t & 15;
        const unsigned short* bnode = bucket + (size_t)(row0 + n) * (NREP * CAP);
        #pragma unroll
        for (int rep = 0; rep < NREP; ++rep) {
            int m = mcnt[n][rep];
            int base = moff[n][rep];
            for (int k = l16; k < m; k += 16)
                clist[n][base + k] = bnode[rep * CAP + k];
        }
    }
    __syncthreads();

    // ---- stage 3: dense gather, 16 lanes/node, 4-deep ILP ----
    {
        const int n = t >> 4, l = t & 15;
        const int deg = moff[n][NREP];
        const size_t lo = l * 8;

        float a0[8], a1[8], a2[8], a3[8];
        {
            u16x8 v = *reinterpret_cast<const u16x8*>(xb + (size_t)(row0 + n) * DIM + lo);
            #pragma unroll
            for (int j = 0; j < 8; ++j) { a0[j] = bf2f(v[j]); a1[j] = 0.f; a2[j] = 0.f; a3[j] = 0.f; }
        }
        int k = 0;
        for (; k + 4 <= deg; k += 4) {
            int c0 = clist[n][k + 0];
            int c1 = clist[n][k + 1];
            int c2 = clist[n][k + 2];
            int c3 = clist[n][k + 3];
            u16x8 v0 = *reinterpret_cast<const u16x8*>(xb + (size_t)c0 * DIM + lo);
            u16x8 v1 = *reinterpret_cast<const u16x8*>(xb + (size_t)c1 * DIM + lo);
            u16x8 v2 = *reinterpret_cast<const u16x8*>(xb + (size_t)c2 * DIM + lo);
            u16x8 v3 = *reinterpret_cast<const u16x8*>(xb + (size_t)c3 * DIM + lo);
            #pragma unroll
            for (int j = 0; j < 8; ++j) {
                a0[j] += bf2f(v0[j]);
                a1[j] += bf2f(v1[j]);
                a2[j] += bf2f(v2[j]);
                a3[j] += bf2f(v3[j]);
            }
        }
        for (; k < deg; ++k) {
            int c = clist[n][k];
            u16x8 v = *reinterpret_cast<const u16x8*>(xb + (size_t)c * DIM + lo);
            #pragma unroll
            for (int j = 0; j < 8; ++j) a0[j] += bf2f(v[j]);
        }
        u16x8 pk;
        #pragma unroll
        for (int j = 0; j < 8; ++j) pk[j] = f2bf((a0[j] + a1[j]) + (a2[j] + a3[j]));
        *reinterpret_cast<u16x8*>(&aggs[n][l * 8]) = pk;
    }
    __syncthreads();

    // ---- stage 4: MLP, wave w owns cols [32w, 32w+32) of both layers ----
    const int wid  = t >> 6;
    const int lane = t & 63;
    const int r16  = lane & 15;
    const int kg   = lane >> 4;
    const int drow = kg * 4;

    bf16x8 af[4];
    #pragma unroll
    for (int kt = 0; kt < 4; ++kt)
        af[kt] = *reinterpret_cast<const bf16x8*>(&aggs[r16][kt * 32 + kg * 8]);

    const f32x4 zero = {0.f, 0.f, 0.f, 0.f};
    f32x4 acc1[2] = {zero, zero};
    #pragma unroll
    for (int kt = 0; kt < 4; ++kt) {
        #pragma unroll
        for (int q = 0; q < 2; ++q) {
            int nt = wid * 2 + q;
            bf16x8 w = *reinterpret_cast<const bf16x8*>(
                W1p + ((nt * 4 + kt) * 64 + lane) * 8);
            acc1[q] = __builtin_amdgcn_mfma_f32_16x16x32_bf16(af[kt], w, acc1[q], 0, 0, 0);
        }
    }
    #pragma unroll
    for (int q = 0; q < 2; ++q) {
        int nt = wid * 2 + q;
        float bv = b1[nt * 16 + r16];
        #pragma unroll
        for (int r = 0; r < 4; ++r) {
            float h = fmaxf(acc1[q][r] + bv, 0.0f);
            hbuf[drow + r][nt * 16 + r16] = f2bf(h);
        }
    }
    __syncthreads();

    bf16x8 hf[4];
    #pragma unroll
    for (int kt = 0; kt < 4; ++kt)
        hf[kt] = *reinterpret_cast<const bf16x8*>(&hbuf[r16][kt * 32 + kg * 8]);

    f32x4 acc2[2] = {zero, zero};
    #pragma unroll
    for (int kt = 0; kt < 4; ++kt) {
        #pragma unroll
        for (int q = 0; q < 2; ++q) {
            int nt = wid * 2 + q;
            bf16x8 w = *reinterpret_cast<const bf16x8*>(
                W2p + ((nt * 4 + kt) * 64 + lane) * 8);
            acc2[q] = __builtin_amdgcn_mfma_f32_16x16x32_bf16(hf[kt], w, acc2[q], 0, 0, 0);
        }
    }
    #pragma unroll
    for (int q = 0; q < 2; ++q) {
        int nt = wid * 2 + q;
        float bv = b2[nt * 16 + r16];
        #pragma unroll
        for (int r = 0; r < 4; ++r)
            out[(size_t)(row0 + drow + r) * DIM + nt * 16 + r16] = acc2[q][r] + bv;
    }
}

// ===========================================================================
// FALLBACK PATH (round-2 proven f32 kernels; ws >= 2,682,880 B)
// ===========================================================================
__global__ void fb_zero_kernel(int* __restrict__ p, int n) {
    int i = blockIdx.x * blockDim.x + threadIdx.x;
    if (i < n) p[i] = 0;
}
__global__ void fb_count_kernel(const int* __restrict__ ei, int* __restrict__ deg) {
    int e = blockIdx.x * blockDim.x + threadIdx.x;
    if (e < NE) atomicAdd(&deg[ei[2 * e]], 1);
}
__global__ __launch_bounds__(1024) void fb_scan_kernel(const int* __restrict__ deg,
                                                       int* __restrict__ rowptr) {
    __shared__ int wtot[16];
    const int t = threadIdx.x;
    const int base = t * 10;
    int local[10];
    int s = 0;
    #pragma unroll
    for (int i = 0; i < 10; ++i) {
        int v = (base + i < NN) ? deg[base + i] : 0;
        local[i] = s;
        s += v;
    }
    const int mySum = s;
    #pragma unroll
    for (int off = 1; off < 64; off <<= 1) {
        int v = __shfl_up(s, (unsigned)off, 64);
        if ((t & 63) >= off) s += v;
    }
    if ((t & 63) == 63) wtot[t >> 6] = s;
    __syncthreads();
    if (t == 0) {
        int run = 0;
        #pragma unroll
        for (int i = 0; i < 16; ++i) { int v = wtot[i]; wtot[i] = run; run += v; }
    }
    __syncthreads();
    const int ex = wtot[t >> 6] + (s - mySum);
    #pragma unroll
    for (int i = 0; i < 10; ++i)
        if (base + i < NN) rowptr[base + i] = ex + local[i];
    if (t == 1023) rowptr[NN] = ex + mySum;
}
__global__ void fb_fill_kernel(const int* __restrict__ ei, const int* __restrict__ rowptr,
                               int* __restrict__ fill, int* __restrict__ colidx) {
    int e = blockIdx.x * blockDim.x + threadIdx.x;
    if (e < NE) {
        int r = ei[2 * e], c = ei[2 * e + 1];
        colidx[rowptr[r] + atomicAdd(&fill[r], 1)] = c;
    }
}
__global__ __launch_bounds__(128) void fb_gather_kernel(const float* __restrict__ x,
                                                        const int* __restrict__ rowptr,
                                                        const int* __restrict__ colidx,
                                                        float* __restrict__ agg) {
    const int n = blockIdx.x, j = threadIdx.x;
    const int s = rowptr[n], e = rowptr[n + 1];
    float acc = x[(size_t)n * DIM + j];
    float a0 = 0.f, a1 = 0.f, a2 = 0.f, a3 = 0.f;
    int k = s;
    for (; k + 4 <= e; k += 4) {
        a0 += x[(size_t)colidx[k + 0] * DIM + j];
        a1 += x[(size_t)colidx[k + 1] * DIM + j];
        a2 += x[(size_t)colidx[k + 2] * DIM + j];
        a3 += x[(size_t)colidx[k + 3] * DIM + j];
    }
    for (; k < e; ++k) acc += x[(size_t)colidx[k] * DIM + j];
    agg[(size_t)n * DIM + j] = acc + (a0 + a1) + (a2 + a3);
}
__global__ __launch_bounds__(512) void fb_mlp_kernel(
        const float* __restrict__ agg,
        const float* __restrict__ W1, const float* __restrict__ b1,
        const float* __restrict__ W2, const float* __restrict__ b2,
        float* __restrict__ out) {
    __shared__ float w1s[DIM * DIM];
    __shared__ float w2s[DIM * DIM];
    __shared__ float b1s[DIM], b2s[DIM];
    __shared__ float as[4][DIM], hs[4][DIM];
    for (int i = threadIdx.x; i < DIM * DIM; i += blockDim.x) { w1s[i] = W1[i]; w2s[i] = W2[i]; }
    if (threadIdx.x < DIM) { b1s[threadIdx.x] = b1[threadIdx.x]; b2s[threadIdx.x] = b2[threadIdx.x]; }
    __syncthreads();
    const int r = threadIdx.x >> 7, j = threadIdx.x & 127;
    for (int base = blockIdx.x * 4; base < NN; base += gridDim.x * 4) {
        int rowid = base + r;
        as[r][j] = (rowid < NN) ? agg[(size_t)rowid * DIM + j] : 0.0f;
        __syncthreads();
        float acc = b1s[j];
        #pragma unroll 8
        for (int k = 0; k < DIM; ++k) acc = fmaf(as[r][k], w1s[k * DIM + j], acc);
        hs[r][j] = fmaxf(acc, 0.0f);
        __syncthreads();
        float acc2 = b2s[j];
        #pragma unroll 8
        for (int k = 0; k < DIM; ++k) acc2 = fmaf(hs[r][k], w2s[k * DIM + j], acc2);
        if (rowid < NN) out[(size_t)rowid * DIM + j] = acc2;
        __syncthreads();
    }
}

// ===========================================================================
extern "C" void kernel_launch(void* const* d_in, const int* in_sizes, int n_in,
                              void* d_out, int out_size, void* d_ws, size_t ws_size,
                              hipStream_t stream) {
    const float* x  = (const float*)d_in[0];
    const int*   ei = (const int*)d_in[1];
    const float* W1 = (const float*)d_in[2];
    const float* b1 = (const float*)d_in[3];
    const float* W2 = (const float*)d_in[4];
    const float* b2 = (const float*)d_in[5];
    float* out = (float*)d_out;

    if (ws_size >= WS_NEED) {
        char* ws = (char*)d_ws;
        int* cnt = (int*)ws;
        unsigned short* bucket = (unsigned short*)(ws + OFF_BUCKET);
        unsigned short* xb     = (unsigned short*)(ws + OFF_XB);
        unsigned short* W1p    = (unsigned short*)(ws + OFF_W1P);
        unsigned short* W2p    = (unsigned short*)(ws + OFF_W2P);

        prep_kernel<<<(PREP_ITEMS + 255) / 256, 256, 0, stream>>>(
            W1, W2, x, W1p, W2p, xb, cnt);
        fill_direct_kernel<<<NE / 256, 256, 0, stream>>>(ei, cnt, bucket);
        // ATTRIBUTION PROBE: launch gather_mlp twice (idempotent — reads ws,
        // writes identical out). total ≈ baseline + T_gather_mlp(hot).
        gather_mlp_kernel<<<NTILES, 256, 0, stream>>>(
            xb, cnt, bucket, W1p, W2p, b1, b2, out);
        gather_mlp_kernel<<<NTILES, 256, 0, stream>>>(
            xb, cnt, bucket, W1p, W2p, b1, b2, out);
    } else {
        int* wsI    = (int*)d_ws;
        int* deg    = wsI;
        int* fillc  = wsI + 10240;
        int* rowptr = wsI + 20480;
        int* colidx = wsI + 30720;
        const size_t csr_bytes = (size_t)(30720 + NE) * sizeof(int);
        const size_t agg_bytes = (size_t)NN * DIM * sizeof(float);
        float* agg = (ws_size >= csr_bytes + agg_bytes)
                         ? (float*)((char*)d_ws + csr_bytes) : out;

        fb_zero_kernel<<<(20480 + 255) / 256, 256, 0, stream>>>(deg, 20480);
        fb_count_kernel<<<(NE + 255) / 256, 256, 0, stream>>>(ei, deg);
        fb_scan_kernel<<<1, 1024, 0, stream>>>(deg, rowptr);
        fb_fill_kernel<<<(NE + 255) / 256, 256, 0, stream>>>(ei, rowptr, fillc, colidx);
        fb_gather_kernel<<<NN, 128, 0, stream>>>(x, rowptr, colidx, agg);
        fb_mlp_kernel<<<256, 512, 0, stream>>>(agg, W1, b1, W2, b2, out);
    }
}

// Round 13
// 41.725 us; speedup vs baseline: 1.7418x; 1.7418x over previous
//
#include <hip/hip_runtime.h>

#define NN   10000
#define NE   640000
#define DIM  128
#define NTILES (NN / 16)        // 625
#define NBIN  320               // bins of 32 rows; valid bins 0..312
#define CAPB  4096              // per-bin capacity (mean 2048, 64 sigma)
#define EPB   2048              // edges per binfill block (256 thr x 8)
#define FILL_BLOCKS ((NE + EPB - 1) / EPB)   // 313
#define CLCAP 512               // per-node dense colid list capacity (deg max ~110)
// prep id ranges: [0,32768) weights | [32768,33088) zero bincnt | [33088,193088) x->bf16
#define PREP_ITEMS 193088

typedef __attribute__((ext_vector_type(8))) short bf16x8;
typedef __attribute__((ext_vector_type(8))) unsigned short u16x8;
typedef __attribute__((ext_vector_type(4))) float f32x4;

__device__ inline unsigned short f2bf(float f) {
    unsigned u = __builtin_bit_cast(unsigned, f);
    unsigned r = (u + 0x7fffu + ((u >> 16) & 1u)) >> 16;
    return (unsigned short)r;
}
__device__ inline float bf2f(unsigned short u) {
    return __builtin_bit_cast(float, (unsigned)u << 16);
}

// ===========================================================================
// PRIMARY ws layout (bytes), total 7,869,696:
//   bincnt int[320]              @ 0          (1,280)      zeroed in prep
//   binmem u32[320][4096]        @ 1,280      (5,242,880)  packed (row&31)<<14|col
//   xb     ushort[1,280,000]     @ 5,244,160  (2,560,000)  bf16 of x
//   W1p    ushort[16384]         @ 7,804,160  (32,768)     bf16 MFMA-frag order
//   W2p    ushort[16384]         @ 7,836,928  (32,768)
// ===========================================================================
#define OFF_BINMEM 1280
#define OFF_XB     5244160
#define OFF_W1P    7804160
#define OFF_W2P    7836928
#define WS_NEED    7869696

// --- prep: pack W1/W2 (MFMA B-frag bf16), zero bincnt, convert x -> bf16 ----
// B-frag for mfma_f32_16x16x32_bf16: lane l elem e = B[kt*32+(l>>4)*8+e][nt*16+(l&15)].
__global__ __launch_bounds__(256) void prep_kernel(
        const float* __restrict__ W1, const float* __restrict__ W2,
        const float* __restrict__ x,
        unsigned short* __restrict__ W1p, unsigned short* __restrict__ W2p,
        unsigned short* __restrict__ xb, int* __restrict__ bincnt) {
    int id = blockIdx.x * 256 + threadIdx.x;
    if (id < 32768) {
        const float* W = (id < 16384) ? W1 : W2;
        unsigned short* Wp = (id < 16384) ? W1p : W2p;
        int f = id & 16383;
        int e = f & 7, lane = (f >> 3) & 63, kt = (f >> 9) & 3, nt = f >> 11;
        int kglob = kt * 32 + (lane >> 4) * 8 + e;
        int jglob = nt * 16 + (lane & 15);
        Wp[f] = f2bf(W[kglob * DIM + jglob]);
    } else if (id < 33088) {
        bincnt[id - 32768] = 0;
    } else if (id < PREP_ITEMS) {
        int i = (id - 33088) * 8;
        float4 a = *reinterpret_cast<const float4*>(x + i);
        float4 b = *reinterpret_cast<const float4*>(x + i + 4);
        u16x8 pk;
        pk[0] = f2bf(a.x); pk[1] = f2bf(a.y); pk[2] = f2bf(a.z); pk[3] = f2bf(a.w);
        pk[4] = f2bf(b.x); pk[5] = f2bf(b.y); pk[6] = f2bf(b.z); pk[7] = f2bf(b.w);
        *reinterpret_cast<u16x8*>(xb + i) = pk;
    }
}

// --- binfill: LDS ranks + one device chunk-claim per (block,bin) ------------
// ~100K device atomics total (vs 640K), 640K fast LDS atomics.
__global__ __launch_bounds__(256) void binfill_kernel(
        const int* __restrict__ ei, int* __restrict__ bincnt,
        unsigned* __restrict__ binmem) {
    __shared__ int hist[NBIN];
    __shared__ int base_s[NBIN];
    const int t = threadIdx.x;
    for (int b = t; b < NBIN; b += 256) hist[b] = 0;
    __syncthreads();

    unsigned pk[8];
    int bn[8], rk[8];
    const int e0 = blockIdx.x * EPB;
    #pragma unroll
    for (int i = 0; i < 8; ++i) {
        int idx = e0 + i * 256 + t;
        bn[i] = -1;
        if (idx < NE) {
            int2 rc = *reinterpret_cast<const int2*>(ei + 2 * idx);
            bn[i] = rc.x >> 5;                                  // bin of 32 rows
            pk[i] = ((unsigned)(rc.x & 31) << 14) | (unsigned)rc.y;
            rk[i] = atomicAdd(&hist[bn[i]], 1);                 // LDS rank
        }
    }
    __syncthreads();
    for (int b = t; b < NBIN; b += 256) {
        int h = hist[b];
        base_s[b] = (h > 0) ? atomicAdd(&bincnt[b], h) : 0;     // device chunk claim
    }
    __syncthreads();
    #pragma unroll
    for (int i = 0; i < 8; ++i) {
        if (bn[i] >= 0) {
            int pos = base_s[bn[i]] + rk[i];
            if (pos < CAPB)
                binmem[(size_t)bn[i] * CAPB + pos] = pk[i];
        }
    }
}

// --- fused gather + MLP: bin-segment prologue + dense gather + MFMA MLP -----
// One 256-thread block per 16-node tile (625 blocks). Tile t reads bin t/2
// (contiguous, coalesced), keeps its 16-row half, LDS-ranks into dense clist.
__global__ __launch_bounds__(256) void gather_mlp_kernel(
        const unsigned short* __restrict__ xb,
        const int* __restrict__ bincnt,
        const unsigned* __restrict__ binmem,
        const unsigned short* __restrict__ W1p,
        const unsigned short* __restrict__ W2p,
        const float* __restrict__ b1,
        const float* __restrict__ b2,
        float* __restrict__ out) {
    __shared__ __align__(16) unsigned short aggs[16][136];
    __shared__ __align__(16) unsigned short hbuf[16][136];
    __shared__ __align__(16) unsigned short clist[16][CLCAP];
    __shared__ int lcnt[16];

    const int row0 = blockIdx.x * 16;
    const int t = threadIdx.x;

    // ---- prologue: bin segment -> per-node dense colid lists ----
    if (t < 16) lcnt[t] = 0;
    __syncthreads();
    {
        const int bin  = blockIdx.x >> 1;
        const int half = blockIdx.x & 1;
        int bc = bincnt[bin];
        bc = (bc > CAPB) ? CAPB : bc;
        const unsigned* bm = binmem + (size_t)bin * CAPB;
        for (int k = t; k < bc; k += 256) {
            unsigned p = bm[k];
            int rl = p >> 14;                  // 0..31 within bin
            if ((rl >> 4) == half) {
                int n = rl & 15;
                int slot = atomicAdd(&lcnt[n], 1);
                if (slot < CLCAP)
                    clist[n][slot] = (unsigned short)(p & 0x3FFFu);
            }
        }
    }
    __syncthreads();

    // ---- dense gather: 16 lanes/node, 4-deep ILP (round-9 proven) ----
    {
        const int n = t >> 4, l = t & 15;
        int deg = lcnt[n];
        deg = (deg > CLCAP) ? CLCAP : deg;
        const size_t lo = l * 8;

        float a0[8], a1[8], a2[8], a3[8];
        {
            u16x8 v = *reinterpret_cast<const u16x8*>(xb + (size_t)(row0 + n) * DIM + lo);
            #pragma unroll
            for (int j = 0; j < 8; ++j) { a0[j] = bf2f(v[j]); a1[j] = 0.f; a2[j] = 0.f; a3[j] = 0.f; }
        }
        int k = 0;
        for (; k + 4 <= deg; k += 4) {
            int c0 = clist[n][k + 0];
            int c1 = clist[n][k + 1];
            int c2 = clist[n][k + 2];
            int c3 = clist[n][k + 3];
            u16x8 v0 = *reinterpret_cast<const u16x8*>(xb + (size_t)c0 * DIM + lo);
            u16x8 v1 = *reinterpret_cast<const u16x8*>(xb + (size_t)c1 * DIM + lo);
            u16x8 v2 = *reinterpret_cast<const u16x8*>(xb + (size_t)c2 * DIM + lo);
            u16x8 v3 = *reinterpret_cast<const u16x8*>(xb + (size_t)c3 * DIM + lo);
            #pragma unroll
            for (int j = 0; j < 8; ++j) {
                a0[j] += bf2f(v0[j]);
                a1[j] += bf2f(v1[j]);
                a2[j] += bf2f(v2[j]);
                a3[j] += bf2f(v3[j]);
            }
        }
        for (; k < deg; ++k) {
            int c = clist[n][k];
            u16x8 v = *reinterpret_cast<const u16x8*>(xb + (size_t)c * DIM + lo);
            #pragma unroll
            for (int j = 0; j < 8; ++j) a0[j] += bf2f(v[j]);
        }
        u16x8 pk;
        #pragma unroll
        for (int j = 0; j < 8; ++j) pk[j] = f2bf((a0[j] + a1[j]) + (a2[j] + a3[j]));
        *reinterpret_cast<u16x8*>(&aggs[n][l * 8]) = pk;
    }
    __syncthreads();

    // ---- MLP: wave w owns cols [32w, 32w+32) of both layers ----
    const int wid  = t >> 6;
    const int lane = t & 63;
    const int r16  = lane & 15;
    const int kg   = lane >> 4;
    const int drow = kg * 4;

    bf16x8 af[4];
    #pragma unroll
    for (int kt = 0; kt < 4; ++kt)
        af[kt] = *reinterpret_cast<const bf16x8*>(&aggs[r16][kt * 32 + kg * 8]);

    const f32x4 zero = {0.f, 0.f, 0.f, 0.f};
    f32x4 acc1[2] = {zero, zero};
    #pragma unroll
    for (int kt = 0; kt < 4; ++kt) {
        #pragma unroll
        for (int q = 0; q < 2; ++q) {
            int nt = wid * 2 + q;
            bf16x8 w = *reinterpret_cast<const bf16x8*>(
                W1p + ((nt * 4 + kt) * 64 + lane) * 8);
            acc1[q] = __builtin_amdgcn_mfma_f32_16x16x32_bf16(af[kt], w, acc1[q], 0, 0, 0);
        }
    }
    #pragma unroll
    for (int q = 0; q < 2; ++q) {
        int nt = wid * 2 + q;
        float bv = b1[nt * 16 + r16];
        #pragma unroll
        for (int r = 0; r < 4; ++r) {
            float h = fmaxf(acc1[q][r] + bv, 0.0f);
            hbuf[drow + r][nt * 16 + r16] = f2bf(h);
        }
    }
    __syncthreads();

    bf16x8 hf[4];
    #pragma unroll
    for (int kt = 0; kt < 4; ++kt)
        hf[kt] = *reinterpret_cast<const bf16x8*>(&hbuf[r16][kt * 32 + kg * 8]);

    f32x4 acc2[2] = {zero, zero};
    #pragma unroll
    for (int kt = 0; kt < 4; ++kt) {
        #pragma unroll
        for (int q = 0; q < 2; ++q) {
            int nt = wid * 2 + q;
            bf16x8 w = *reinterpret_cast<const bf16x8*>(
                W2p + ((nt * 4 + kt) * 64 + lane) * 8);
            acc2[q] = __builtin_amdgcn_mfma_f32_16x16x32_bf16(hf[kt], w, acc2[q], 0, 0, 0);
        }
    }
    #pragma unroll
    for (int q = 0; q < 2; ++q) {
        int nt = wid * 2 + q;
        float bv = b2[nt * 16 + r16];
        #pragma unroll
        for (int r = 0; r < 4; ++r)
            out[(size_t)(row0 + drow + r) * DIM + nt * 16 + r16] = acc2[q][r] + bv;
    }
}

// ===========================================================================
// FALLBACK PATH (round-2 proven f32 kernels; ws >= 2,682,880 B)
// ===========================================================================
__global__ void fb_zero_kernel(int* __restrict__ p, int n) {
    int i = blockIdx.x * blockDim.x + threadIdx.x;
    if (i < n) p[i] = 0;
}
__global__ void fb_count_kernel(const int* __restrict__ ei, int* __restrict__ deg) {
    int e = blockIdx.x * blockDim.x + threadIdx.x;
    if (e < NE) atomicAdd(&deg[ei[2 * e]], 1);
}
__global__ __launch_bounds__(1024) void fb_scan_kernel(const int* __restrict__ deg,
                                                       int* __restrict__ rowptr) {
    __shared__ int wtot[16];
    const int t = threadIdx.x;
    const int base = t * 10;
    int local[10];
    int s = 0;
    #pragma unroll
    for (int i = 0; i < 10; ++i) {
        int v = (base + i < NN) ? deg[base + i] : 0;
        local[i] = s;
        s += v;
    }
    const int mySum = s;
    #pragma unroll
    for (int off = 1; off < 64; off <<= 1) {
        int v = __shfl_up(s, (unsigned)off, 64);
        if ((t & 63) >= off) s += v;
    }
    if ((t & 63) == 63) wtot[t >> 6] = s;
    __syncthreads();
    if (t == 0) {
        int run = 0;
        #pragma unroll
        for (int i = 0; i < 16; ++i) { int v = wtot[i]; wtot[i] = run; run += v; }
    }
    __syncthreads();
    const int ex = wtot[t >> 6] + (s - mySum);
    #pragma unroll
    for (int i = 0; i < 10; ++i)
        if (base + i < NN) rowptr[base + i] = ex + local[i];
    if (t == 1023) rowptr[NN] = ex + mySum;
}
__global__ void fb_fill_kernel(const int* __restrict__ ei, const int* __restrict__ rowptr,
                               int* __restrict__ fill, int* __restrict__ colidx) {
    int e = blockIdx.x * blockDim.x + threadIdx.x;
    if (e < NE) {
        int r = ei[2 * e], c = ei[2 * e + 1];
        colidx[rowptr[r] + atomicAdd(&fill[r], 1)] = c;
    }
}
__global__ __launch_bounds__(128) void fb_gather_kernel(const float* __restrict__ x,
                                                        const int* __restrict__ rowptr,
                                                        const int* __restrict__ colidx,
                                                        float* __restrict__ agg) {
    const int n = blockIdx.x, j = threadIdx.x;
    const int s = rowptr[n], e = rowptr[n + 1];
    float acc = x[(size_t)n * DIM + j];
    float a0 = 0.f, a1 = 0.f, a2 = 0.f, a3 = 0.f;
    int k = s;
    for (; k + 4 <= e; k += 4) {
        a0 += x[(size_t)colidx[k + 0] * DIM + j];
        a1 += x[(size_t)colidx[k + 1] * DIM + j];
        a2 += x[(size_t)colidx[k + 2] * DIM + j];
        a3 += x[(size_t)colidx[k + 3] * DIM + j];
    }
    for (; k < e; ++k) acc += x[(size_t)colidx[k] * DIM + j];
    agg[(size_t)n * DIM + j] = acc + (a0 + a1) + (a2 + a3);
}
__global__ __launch_bounds__(512) void fb_mlp_kernel(
        const float* __restrict__ agg,
        const float* __restrict__ W1, const float* __restrict__ b1,
        const float* __restrict__ W2, const float* __restrict__ b2,
        float* __restrict__ out) {
    __shared__ float w1s[DIM * DIM];
    __shared__ float w2s[DIM * DIM];
    __shared__ float b1s[DIM], b2s[DIM];
    __shared__ float as[4][DIM], hs[4][DIM];
    for (int i = threadIdx.x; i < DIM * DIM; i += blockDim.x) { w1s[i] = W1[i]; w2s[i] = W2[i]; }
    if (threadIdx.x < DIM) { b1s[threadIdx.x] = b1[threadIdx.x]; b2s[threadIdx.x] = b2[threadIdx.x]; }
    __syncthreads();
    const int r = threadIdx.x >> 7, j = threadIdx.x & 127;
    for (int base = blockIdx.x * 4; base < NN; base += gridDim.x * 4) {
        int rowid = base + r;
        as[r][j] = (rowid < NN) ? agg[(size_t)rowid * DIM + j] : 0.0f;
        __syncthreads();
        float acc = b1s[j];
        #pragma unroll 8
        for (int k = 0; k < DIM; ++k) acc = fmaf(as[r][k], w1s[k * DIM + j], acc);
        hs[r][j] = fmaxf(acc, 0.0f);
        __syncthreads();
        float acc2 = b2s[j];
        #pragma unroll 8
        for (int k = 0; k < DIM; ++k) acc2 = fmaf(hs[r][k], w2s[k * DIM + j], acc2);
        if (rowid < NN) out[(size_t)rowid * DIM + j] = acc2;
        __syncthreads();
    }
}

// ===========================================================================
extern "C" void kernel_launch(void* const* d_in, const int* in_sizes, int n_in,
                              void* d_out, int out_size, void* d_ws, size_t ws_size,
                              hipStream_t stream) {
    const float* x  = (const float*)d_in[0];
    const int*   ei = (const int*)d_in[1];
    const float* W1 = (const float*)d_in[2];
    const float* b1 = (const float*)d_in[3];
    const float* W2 = (const float*)d_in[4];
    const float* b2 = (const float*)d_in[5];
    float* out = (float*)d_out;

    if (ws_size >= WS_NEED) {
        char* ws = (char*)d_ws;
        int* bincnt = (int*)ws;
        unsigned* binmem = (unsigned*)(ws + OFF_BINMEM);
        unsigned short* xb  = (unsigned short*)(ws + OFF_XB);
        unsigned short* W1p = (unsigned short*)(ws + OFF_W1P);
        unsigned short* W2p = (unsigned short*)(ws + OFF_W2P);

        prep_kernel<<<(PREP_ITEMS + 255) / 256, 256, 0, stream>>>(
            W1, W2, x, W1p, W2p, xb, bincnt);
        binfill_kernel<<<FILL_BLOCKS, 256, 0, stream>>>(ei, bincnt, binmem);
        gather_mlp_kernel<<<NTILES, 256, 0, stream>>>(
            xb, bincnt, binmem, W1p, W2p, b1, b2, out);
    } else {
        int* wsI    = (int*)d_ws;
        int* deg    = wsI;
        int* fillc  = wsI + 10240;
        int* rowptr = wsI + 20480;
        int* colidx = wsI + 30720;
        const size_t csr_bytes = (size_t)(30720 + NE) * sizeof(int);
        const size_t agg_bytes = (size_t)NN * DIM * sizeof(float);
        float* agg = (ws_size >= csr_bytes + agg_bytes)
                         ? (float*)((char*)d_ws + csr_bytes) : out;

        fb_zero_kernel<<<(20480 + 255) / 256, 256, 0, stream>>>(deg, 20480);
        fb_count_kernel<<<(NE + 255) / 256, 256, 0, stream>>>(ei, deg);
        fb_scan_kernel<<<1, 1024, 0, stream>>>(deg, rowptr);
        fb_fill_kernel<<<(NE + 255) / 256, 256, 0, stream>>>(ei, rowptr, fillc, colidx);
        fb_gather_kernel<<<NN, 128, 0, stream>>>(x, rowptr, colidx, agg);
        fb_mlp_kernel<<<256, 512, 0, stream>>>(agg, W1, b1, W2, b2, out);
    }
}